// Round 10
// baseline (272.184 us; speedup 1.0000x reference)
//
#include <hip/hip_runtime.h>
#include <stdint.h>

// Problem dims
#define BDIM 8
#define CDIM 32
#define NDIM 512
#define TDIM 168
#define KG   2048          // GEMM K = 4 slices * 512 nodes
#define NJ   43008         // 1344 (b,l) * 32 o   (column order jj = (b*168+l)*32 + o)
#define ALPHA_ 0.05f
#define BETA_  0.95f

typedef __attribute__((ext_vector_type(8))) short short8;
typedef __attribute__((ext_vector_type(4))) float f32x4;
typedef __attribute__((ext_vector_type(2))) float f2v;
typedef __attribute__((ext_vector_type(4))) unsigned short u16x4;

__device__ __forceinline__ unsigned short f2bf(float f) {
  union { float f; unsigned int u; } v; v.f = f;
  unsigned int r = v.u + 0x7fffu + ((v.u >> 16) & 1u);
  return (unsigned short)(r >> 16);
}
__device__ __forceinline__ float bf2f(unsigned short h) {
  union { unsigned int u; float f; } v; v.u = ((unsigned int)h) << 16;
  return v.f;
}
__device__ __forceinline__ void gload_lds16(const void* g, void* l) {
  __builtin_amdgcn_global_load_lds((const __attribute__((address_space(1))) void*)g,
                                   (__attribute__((address_space(3))) void*)l, 16, 0, 0);
}

// ---- prep: row sums of (adp + I) and (adp^T + I) ----
__global__ void gc_prep(const float* __restrict__ adp, float* __restrict__ rs) {
  int v = blockIdx.x, t = threadIdx.x;
  float sA = 0.f, sB = 0.f;
  for (int w = t; w < NDIM; w += 256) { sA += adp[v * NDIM + w]; sB += adp[w * NDIM + v]; }
  __shared__ float red[2][256];
  red[0][t] = sA; red[1][t] = sB; __syncthreads();
  for (int s = 128; s > 0; s >>= 1) {
    if (t < s) { red[0][t] += red[0][t + s]; red[1][t] += red[1][t + s]; }
    __syncthreads();
  }
  if (t == 0) { rs[v] = 1.f + red[0][0]; rs[NDIM + v] = 1.f + red[1][0]; }
}

// ---- build A (slice 0) and A' (slice 2) into chunked G2[(k>>3)][n][8], plus fp32 copies ----
__global__ void gc_build(const float* __restrict__ adp, const float* __restrict__ rs,
                         float* __restrict__ Af, unsigned short* __restrict__ G2) {
  int v = blockIdx.x, t = threadIdx.x;
  float ra = 1.f / rs[v], rb = 1.f / rs[NDIM + v];
  for (int w = t; w < NDIM; w += 256) {
    float d = (v == w) ? 1.f : 0.f;
    float a  = (adp[v * NDIM + w] + d) * ra;   // A[v][w]
    float a2 = (adp[w * NDIM + v] + d) * rb;   // A'[v][w]
    Af[(size_t)v * NDIM + w] = a;
    Af[(size_t)NDIM * NDIM + (size_t)v * NDIM + w] = a2;
    G2[(size_t)(((0 * 64) + (w >> 3)) * 512 + v) * 8 + (w & 7)] = f2bf(a);
    G2[(size_t)(((2 * 64) + (w >> 3)) * 512 + v) * 8 + (w & 7)] = f2bf(a2);
  }
}

// ---- A^2 (slice 1) and A'^2 (slice 3) into G2; 512 blocks of 32x32 tiles ----
__global__ __launch_bounds__(256, 4) void gc_sq2(const float* __restrict__ Af,
                                                 unsigned short* __restrict__ G2) {
  int bid = blockIdx.x;
  int mat = bid >> 8, tile = bid & 255;
  int v0 = (tile >> 4) * 32, w0 = (tile & 15) * 32;
  const float* M = Af + (size_t)mat * NDIM * NDIM;
  __shared__ float T1[64][33];
  __shared__ float T2[64][33];
  int t = threadIdx.x;
  int ty = t >> 4, tx = t & 15;
  float a00 = 0.f, a01 = 0.f, a10 = 0.f, a11 = 0.f;
  for (int u0 = 0; u0 < NDIM; u0 += 64) {
    #pragma unroll
    for (int q = 0; q < 8; ++q) {
      int id = q * 256 + t;
      int c = id & 63, r = id >> 6;
      T1[c][r] = M[(size_t)(v0 + r) * NDIM + u0 + c];
      int u = id >> 5, w = id & 31;
      T2[u][w] = M[(size_t)(u0 + u) * NDIM + w0 + w];
    }
    __syncthreads();
    for (int u = 0; u < 64; ++u) {
      f2v a = *(const f2v*)&T1[u][ty * 2];
      f2v b = *(const f2v*)&T2[u][tx * 2];
      a00 += a[0] * b[0]; a01 += a[0] * b[1];
      a10 += a[1] * b[0]; a11 += a[1] * b[1];
    }
    __syncthreads();
  }
  int sl = mat ? 3 : 1;
  int v = v0 + ty * 2, w = w0 + tx * 2;
  size_t cb = (size_t)(sl * 64 + (w >> 3)) * 512;
  size_t cb1 = (size_t)(sl * 64 + ((w + 1) >> 3)) * 512;
  G2[(cb  + v    ) * 8 + (w & 7)]       = f2bf(a00);
  G2[(cb1 + v    ) * 8 + ((w + 1) & 7)] = f2bf(a01);
  G2[(cb  + v + 1) * 8 + (w & 7)]       = f2bf(a10);
  G2[(cb1 + v + 1) * 8 + ((w + 1) & 7)] = f2bf(a11);
}

// ---- folded channel-mix matrices, bf16: Ub[160][32] rows = {U1,U2,V1,V2,U0'}; bias = b1+b2 ----
__global__ void gc_ucat(const float* __restrict__ W1, const float* __restrict__ b1,
                        const float* __restrict__ W2, const float* __restrict__ b2,
                        unsigned short* __restrict__ Ub, float* __restrict__ bias) {
  int t = threadIdx.x;
  for (int idx = t; idx < 160 * 32; idx += 256) {
    int ko = idx >> 5, c = idx & 31, o = ko & 31, s = ko >> 5;
    float v;
    if (s == 0)      v = BETA_ * (W1[o * 96 + 32 + c] + ALPHA_ * W1[o * 96 + 64 + c]);
    else if (s == 1) v = BETA_ * BETA_ * W1[o * 96 + 64 + c];
    else if (s == 2) v = BETA_ * (W2[o * 96 + 32 + c] + ALPHA_ * W2[o * 96 + 64 + c]);
    else if (s == 3) v = BETA_ * BETA_ * W2[o * 96 + 64 + c];
    else             v = W1[o * 96 + c] + ALPHA_ * (W1[o * 96 + 32 + c] + W1[o * 96 + 64 + c])
                       + W2[o * 96 + c] + ALPHA_ * (W2[o * 96 + 32 + c] + W2[o * 96 + 64 + c]);
    Ub[idx] = f2bf(v);
  }
  if (t < 32) bias[t] = b1[t] + b2[t];
}

// ---- channel-mix via MFMA, direct stores in (b,l,o)-major column order ----
// Pg[kbg 0..320)[jj][8w]; slices 0..3 = GEMM B-panel, slice 4 = identity (old R0).
// grid 1024 = 8 b * 32 wt(16 w) * 4 lq(42 l); 256 threads (4 waves)
__global__ __launch_bounds__(256, 2) void gc_mix6(const float* __restrict__ x,
    const unsigned short* __restrict__ Ub, unsigned short* __restrict__ Pg) {
  __shared__ __align__(16) unsigned short xs[26880];  // [42 ll][16 w'][40 c pad]
  int bid = blockIdx.x;
  int lq = bid & 3, wt = (bid >> 2) & 31, b = bid >> 7;
  int l0 = lq * 42, w0 = wt * 16;
  int tid = threadIdx.x, wv = tid >> 6, lane = tid & 63;
  int l15 = lane & 15, hi = lane >> 4;

  // stage x[b][:][w0..w0+16)[l0..l0+42) -> xs (coalesced reads, swizzled 2B writes)
  #pragma unroll 4
  for (int e = 0; e < 84; ++e) {
    int id = e * 256 + tid;
    int c = id / 672, rem = id - c * 672;
    int w = rem / 42, ll = rem - w * 42;
    float v = x[(size_t)((b * 32 + c) * 512 + w0 + w) * 168 + l0 + ll];
    xs[(ll * 16 + (w ^ (ll & 15))) * 40 + c] = f2bf(v);
  }
  __syncthreads();

  // B-operand fragments from Ub (col=l15 -> o, k=hi*8.. -> c)
  short8 uF[10];
  #pragma unroll
  for (int mt = 0; mt < 10; ++mt)
    uF[mt] = *(const short8*)(Ub + (size_t)(mt * 16 + l15) * 32 + hi * 8);

  for (int i = 0; i < 11; ++i) {
    int li = wv + 4 * i;
    if (li >= 42) break;
    int l = l0 + li;
    short8 xf = *(const short8*)&xs[(li * 16 + (l15 ^ (li & 15))) * 40 + hi * 8];
    size_t jbase = (size_t)(b * 168 + l) * 32;
    #pragma unroll
    for (int mt = 0; mt < 10; ++mt) {
      f32x4 z = {0.f, 0.f, 0.f, 0.f};
      f32x4 p = __builtin_amdgcn_mfma_f32_16x16x32_bf16(xf, uF[mt], z, 0, 0, 0);
      size_t kbg = (size_t)((mt >> 1) * 64 + wt * 2 + (hi >> 1));
      size_t jj = jbase + ((mt & 1) << 4) + l15;
      u16x4 pk = { f2bf(p[0]), f2bf(p[1]), f2bf(p[2]), f2bf(p[3]) };
      *(u16x4*)(Pg + (kbg * NJ + jj) * 8 + (hi & 1) * 4) = pk;
    }
  }
}

// ---- main GEMM, m201-style fine-phase schedule ----
// C[512 n][43008 jj] = G[512][2048] * P; epilogue adds P4[n][jj] + bias via LDS slab.
// 448 blocks (2 mt * 224 jt), 512 threads = 8 waves (2M x 4N), wave tile 128x48.
// BK=32 subtiles, TRIPLE-buffered (84KB, 1 block/CU, 2 waves/SIMD). Per subtile:
// 2 phases of {ds_reads + stage-issue -> barrier -> lgkm0 -> setprio 12 MFMA} ;
// counted vmcnt(3) once per subtile, placed before the trailing barrier (collective).
__global__ __launch_bounds__(512, 2) void gc_gemm10(const unsigned short* __restrict__ G2,
    const unsigned short* __restrict__ Pg, const float* __restrict__ bias,
    float* __restrict__ out) {
  int bid = blockIdx.x;
  int swz = (bid & 7) * 56 + (bid >> 3);   // XCD-chunked bijective swizzle (448 = 8*56)
  int mt = swz & 1, jt = swz >> 1;         // mt fastest: B-panel pair adjacent on same XCD
  int n0 = mt * 256, jj0 = jt * 192;

  __shared__ __align__(16) unsigned short SH[43008];   // 84 KB
  unsigned short* AbBase = SH;             // 3 bufs x [kb 4][n 256][8] = 3 x 8192
  unsigned short* BbBase = SH + 24576;     // 3 bufs x [kb 4][j 192][8] = 3 x 6144

  int tid = threadIdx.x, lane = tid & 63, wid = tid >> 6;
  int wm = wid >> 2, wn = wid & 3;
  int l15 = lane & 15, hi = lane >> 4;

  // staging assignments (16B chunks per K-32 subtile)
  const unsigned short* srcA[2]; int dA[2];
  #pragma unroll
  for (int q = 0; q < 2; ++q) {
    int f = q * 512 + tid;                 // kb = f>>8, nloc = f&255
    srcA[q] = G2 + ((size_t)(f >> 8) * 512 + n0 + (f & 255)) * 8;
    dA[q] = f * 8;
  }
  int g0 = tid;                            // B chunk 0..511
  int kb0 = g0 / 192, j0c = g0 - kb0 * 192;
  const unsigned short* srcB0 = Pg + ((size_t)kb0 * NJ + jj0 + j0c) * 8;
  int dB0 = g0 * 8;
  int g1 = 512 + (tid & 255);              // B chunk 512..767 (tid<256 only)
  int kb1 = g1 / 192, j1c = g1 - kb1 * 192;
  const unsigned short* srcB1 = Pg + ((size_t)kb1 * NJ + jj0 + j1c) * 8;
  int dB1 = g1 * 8;
  const bool doB1 = (tid < 256);           // wave-uniform

  const size_t strideA = 4 * 512 * 8;      // shorts per K-32 subtile
  const size_t strideB = (size_t)4 * NJ * 8;

  f32x4 acc[8][3] = {};

  // prologue: subtiles 0 -> buf0, 1 -> buf1
  #pragma unroll
  for (int tp = 0; tp < 2; ++tp) {
    gload_lds16(srcA[0] + tp * strideA, AbBase + tp * 8192 + dA[0]);
    gload_lds16(srcA[1] + tp * strideA, AbBase + tp * 8192 + dA[1]);
    gload_lds16(srcB0 + tp * strideB, BbBase + tp * 6144 + dB0);
    if (doB1) gload_lds16(srcB1 + tp * strideB, BbBase + tp * 6144 + dB1);
  }
  asm volatile("s_waitcnt vmcnt(3)" ::: "memory");     // subtile 0 landed (all threads)
  __builtin_amdgcn_s_barrier();

  int aoffs = (wm * 128 + l15) * 8;        // + mi*128 + hi*2048
  int boffs = (wn * 48 + l15) * 8;         // + nj*128 + hi*1536

  int cur = 0;
  for (int t = 0; t < 64; ++t) {
    const unsigned short* ap = AbBase + cur * 8192;
    const unsigned short* bp = BbBase + cur * 6144;
    int nxt = cur - 1; if (nxt < 0) nxt = 2;   // buffer of subtile t-1 (reads done)

    // ---- phase 0: aF[0..3] + bF[0..2], A-stage of t+2, 12 MFMA ----
    short8 aF[4], bF[3];
    #pragma unroll
    for (int mi = 0; mi < 4; ++mi) aF[mi] = *(const short8*)&ap[hi * 2048 + aoffs + mi * 128];
    #pragma unroll
    for (int nj = 0; nj < 3; ++nj) bF[nj] = *(const short8*)&bp[hi * 1536 + boffs + nj * 128];
    if (t < 62) {
      gload_lds16(srcA[0] + (size_t)(t + 2) * strideA, AbBase + nxt * 8192 + dA[0]);
      gload_lds16(srcA[1] + (size_t)(t + 2) * strideA, AbBase + nxt * 8192 + dA[1]);
    }
    __builtin_amdgcn_s_barrier();
    asm volatile("s_waitcnt lgkmcnt(0)" ::: "memory");
    __builtin_amdgcn_s_setprio(1);
    #pragma unroll
    for (int mi = 0; mi < 4; ++mi)
      #pragma unroll
      for (int nj = 0; nj < 3; ++nj)
        acc[mi][nj] = __builtin_amdgcn_mfma_f32_16x16x32_bf16(aF[mi], bF[nj], acc[mi][nj], 0, 0, 0);
    __builtin_amdgcn_s_setprio(0);
    __builtin_amdgcn_s_barrier();

    // ---- phase 1: aF[4..7] (bF reused), B-stage of t+2, 12 MFMA ----
    short8 aG[4];
    #pragma unroll
    for (int mi = 0; mi < 4; ++mi) aG[mi] = *(const short8*)&ap[hi * 2048 + aoffs + (mi + 4) * 128];
    if (t < 62) {
      gload_lds16(srcB0 + (size_t)(t + 2) * strideB, BbBase + nxt * 6144 + dB0);
      if (doB1) gload_lds16(srcB1 + (size_t)(t + 2) * strideB, BbBase + nxt * 6144 + dB1);
    }
    __builtin_amdgcn_s_barrier();
    asm volatile("s_waitcnt lgkmcnt(0)" ::: "memory");
    __builtin_amdgcn_s_setprio(1);
    #pragma unroll
    for (int mi = 0; mi < 4; ++mi)
      #pragma unroll
      for (int nj = 0; nj < 3; ++nj)
        acc[mi + 4][nj] = __builtin_amdgcn_mfma_f32_16x16x32_bf16(aG[mi], bF[nj], acc[mi + 4][nj], 0, 0, 0);
    __builtin_amdgcn_s_setprio(0);
    // counted drain for subtile t+1 (collectivized by the trailing barrier)
    if (t < 62)       { asm volatile("s_waitcnt vmcnt(3)" ::: "memory"); }
    else if (t == 62) { asm volatile("s_waitcnt vmcnt(0)" ::: "memory"); }
    __builtin_amdgcn_s_barrier();

    cur = cur + 1; if (cur == 3) cur = 0;
  }

  // ---- epilogue: 4 slabs of 64 n; LDS transpose; out = C + P4 + bias (24B l-runs) ----
  int bl0 = jt * 6;                        // 6 consecutive (b,l), never crosses b (168%6==0)
  int bq = bl0 / 168, l0g = bl0 - bq * 168;
  float* Cs = (float*)SH;                  // 64*194*4 = 49.7KB <= 84KB
  __syncthreads();
  for (int s = 0; s < 4; ++s) {
    if (wm == (s >> 1)) {
      int mio = (s & 1) * 4;
      #pragma unroll
      for (int mi = 0; mi < 4; ++mi)
        #pragma unroll
        for (int nj = 0; nj < 3; ++nj) {
          int row = mi * 16 + hi * 4;
          int col = wn * 48 + nj * 16 + l15;
          #pragma unroll
          for (int r = 0; r < 4; ++r)
            Cs[(row + r) * 194 + col] = acc[mio + mi][nj][r];
        }
    }
    __syncthreads();
    #pragma unroll
    for (int q = 0; q < 4; ++q) {
      int rid = q * 512 + tid;
      int o = rid & 31, nl = rid >> 5;
      int n_g = n0 + s * 64 + nl;
      float bs = bias[o];
      const unsigned short* p4 = Pg + (((size_t)256 + (n_g >> 3)) * NJ + jj0 + o) * 8 + (n_g & 7);
      float* op = out + ((size_t)(bq * 32 + o) * 512 + n_g) * 168 + l0g;
      float v[6];
      #pragma unroll
      for (int lf = 0; lf < 6; ++lf)
        v[lf] = Cs[nl * 194 + lf * 32 + o] + bf2f(p4[(size_t)lf * 256]) + bs;
      f2v v0 = {v[0], v[1]}, v1 = {v[2], v[3]}, v2 = {v[4], v[5]};
      *(f2v*)op = v0; *(f2v*)(op + 2) = v1; *(f2v*)(op + 4) = v2;
    }
    __syncthreads();
  }
}

extern "C" void kernel_launch(void* const* d_in, const int* in_sizes, int n_in,
                              void* d_out, int out_size, void* d_ws, size_t ws_size,
                              hipStream_t stream) {
  const float* x   = (const float*)d_in[0];
  const float* adp = (const float*)d_in[1];
  const float* W1  = (const float*)d_in[2];
  const float* b1  = (const float*)d_in[3];
  const float* W2  = (const float*)d_in[4];
  const float* b2  = (const float*)d_in[5];
  float* out = (float*)d_out;

  char* w = (char*)d_ws;
  unsigned short* Pg  = (unsigned short*)(w);                  // 220,200,960 B (5 slices)
  unsigned short* G2  = (unsigned short*)(w + 220200960ULL);   //   2,097,152 B
  float* Af           = (float*)(w + 222298112ULL);            //   2,097,152 B
  float* rs           = (float*)(w + 224395264ULL);            //       4,096 B
  unsigned short* Ub  = (unsigned short*)(w + 224399360ULL);   //      16,384 B (10,240 used)
  float* bias         = (float*)(w + 224415744ULL);            //         128 B
  if (ws_size < 224415872ULL) return;                          // need ~214 MiB

  gc_prep<<<512, 256, 0, stream>>>(adp, rs);
  gc_build<<<512, 256, 0, stream>>>(adp, rs, Af, G2);
  gc_sq2<<<512, 256, 0, stream>>>(Af, G2);
  gc_ucat<<<1, 256, 0, stream>>>(W1, b1, W2, b2, Ub, bias);
  gc_mix6<<<1024, 256, 0, stream>>>(x, Ub, Pg);
  gc_gemm10<<<448, 512, 0, stream>>>(G2, Pg, bias, out);
}